// Round 13
// baseline (192.412 us; speedup 1.0000x reference)
//
#include <hip/hip_runtime.h>
#include <math.h>

#define S_LEN 8192
#define DHEAD 64
#define NBATCH 4
#define BK 32
#define KIT 128           // 4096 keys per pair / BK

typedef unsigned short u16;
typedef unsigned int u32;
typedef __attribute__((ext_vector_type(8))) _Float16 half8;
typedef __attribute__((ext_vector_type(2))) __fp16 fp16x2;
typedef __attribute__((ext_vector_type(4))) float f32x4;

union HU8 { int4 i4; half8 h8; u32 w[4]; };
union H2U { fp16x2 h2; u32 w; };
union HU  { _Float16 h; u16 u; };

#if __has_builtin(__builtin_amdgcn_exp2f)
#define EXP2(x) __builtin_amdgcn_exp2f(x)
#else
#define EXP2(x) exp2f(x)
#endif

// float -> f16 RNE
__device__ __forceinline__ u16 f2h(float f) {
    HU x; x.h = (_Float16)f; return x.u;
}
// two floats -> packed f16x2, single v_cvt_pkrtz_f16_f32
__device__ __forceinline__ u32 packh2(float a, float b) {
    H2U x; x.h2 = __builtin_amdgcn_cvt_pkrtz(a, b); return x.w;
}

#define LD_ACQ(p)    __hip_atomic_load((p), __ATOMIC_ACQUIRE, __HIP_MEMORY_SCOPE_WORKGROUP)
#define ST_REL(p, v) __hip_atomic_store((p), (v), __ATOMIC_RELEASE, __HIP_MEMORY_SCOPE_WORKGROUP)

// ---------------------------------------------------------------------------
// Prep: blocks [0,1024) pack K and V (both f16) of one 32-key tile
// (b = bid>>8, t = bid&255) into MFMA-fragment order:
//   blob[b][t] (8 KB) = K chunks j=0..3 (j=kt*2+ds) then V chunks dt=0..3,
//   chunk = 64 lanes x 16 B, exact flash lane order:
//     K: lane(low,h) -> K[b][t*32 + 8*(low>>2)+4*kt+(low&3)][ds*32+h*8+0..7]
//     V: lane(low,h) -> V[b][t*32 + h*8 + 0..7][dt*16+low]
// Blocks [1024,1056): Julia bias in f64 (matches numpy), fixed max M=20
// folded: bias2[k] = log(exp(et*scale)+1e-8)*log2e - 20.
// ---------------------------------------------------------------------------
__global__ void prep_kernel(const float* __restrict__ K, const float* __restrict__ V,
                            const float* crp, const float* cip, const float* scp,
                            u16* __restrict__ blob, float* __restrict__ bias2) {
    int bid = blockIdx.x, tid = threadIdx.x;
    if (bid < 1024) {
        int b = bid >> 8, t = bid & 255;
        __shared__ float Kt[32 * 64];
        __shared__ float Vt[32 * 65];          // padded rows: conflict-free col reads
        int row = tid >> 3, c8 = (tid & 7) * 8;
        const float* ks = K + ((size_t)(b * S_LEN + t * 32 + row)) * 64 + c8;
        const float* vs = V + ((size_t)(b * S_LEN + t * 32 + row)) * 64 + c8;
        float4 ka = *(const float4*)ks, kb4 = *(const float4*)(ks + 4);
        float4 va = *(const float4*)vs, vb4 = *(const float4*)(vs + 4);
        *(float4*)&Kt[row * 64 + c8] = ka;
        *(float4*)&Kt[row * 64 + c8 + 4] = kb4;
        float* vr = &Vt[row * 65 + c8];
        vr[0] = va.x; vr[1] = va.y; vr[2] = va.z; vr[3] = va.w;
        vr[4] = vb4.x; vr[5] = vb4.y; vr[6] = vb4.z; vr[7] = vb4.w;
        __syncthreads();

        int j = tid >> 6, lane = tid & 63, low = lane & 15, h = lane >> 4;
        u16* tb = blob + ((size_t)(b * 256 + t)) * 4096;   // u16 elems (8 KB)
        {   // K chunk j = kt*2 + ds  (f16)
            int kt = j >> 1, ds = j & 1;
            int krow = 8 * (low >> 2) + 4 * kt + (low & 3);
            const float* src = &Kt[krow * 64 + ds * 32 + h * 8];
            u32 wds[4];
#pragma unroll
            for (int i = 0; i < 4; ++i)
                wds[i] = (u32)f2h(src[2 * i]) | ((u32)f2h(src[2 * i + 1]) << 16);
            *(int4*)(tb + j * 512 + lane * 8) = make_int4(wds[0], wds[1], wds[2], wds[3]);
        }
        {   // V chunk dt = j  (f16)
            int col = j * 16 + low;
            u32 wds[4];
#pragma unroll
            for (int i = 0; i < 4; ++i) {
                float a = Vt[(h * 8 + 2 * i) * 65 + col];
                float c = Vt[(h * 8 + 2 * i + 1) * 65 + col];
                wds[i] = (u32)f2h(a) | ((u32)f2h(c) << 16);
            }
            *(int4*)(tb + 2048 + j * 512 + lane * 8) = make_int4(wds[0], wds[1], wds[2], wds[3]);
        }
    } else {
#pragma clang fp contract(off)
        int i = (bid - 1024) * 256 + tid;
        double cr = (double)crp[0], ci = (double)cip[0], sc = (double)scp[0];
        double step = 4.0 / (double)(S_LEN - 1);
        double x = (i == S_LEN - 1) ? 2.0 : (-2.0 + step * (double)i);
        double zr = x, zi = 0.0, et = 1.0;
        bool esc = false;
        for (int it = 0; it < 64; ++it) {
            double nzr = zr * zr - zi * zi + cr;
            double nzi = 2.0 * zr * zi + ci;
            if (!esc) { zr = nzr; zi = nzi; }
            double m2 = zr * zr + zi * zi;
            if (!esc && m2 > 4.0) { et = (double)it / 64.0; esc = true; }
        }
        double bias = log(exp(et * sc) + 1e-8);
        bias2[i] = (float)(bias * 1.4426950408889634 - 20.0);
    }
}

// ---------------------------------------------------------------------------
// Flash: PRODUCER/CONSUMER WAVE SPECIALIZATION.
//   Evidence base: R7-R12 showed wall = matrix-demand + VALU-demand (zero
//   overlap); every same-wave interleave failed (R8 spill, R9 null, R11
//   -19%), blind inter-wave skew null (R12).  m114 (guide): a pure-MFMA
//   wave and a pure-VALU wave on one CU DO overlap fully.  So: separate
//   the pipes BY WAVE ROLE.
//
//   grid 256 (1 block/CU), block 512 = 8 waves = 4 pairs.  Block covers
//   128 q x all 8192 keys; pair p=(qh,kq) covers 64 q x 4096 keys
//   (KIT=128 tiles of BK=32).  Roles: wid<4 -> M-wave (all 32 MFMA/iter:
//   QK -> st to LDS; pf from LDS -> PV; zero exp2), wid>=4 -> V-wave
//   (st from LDS -> exp2/pack/lsum -> pf to LDS; zero MFMA).  Under
//   round-robin wave->SIMD (SIMD=wid&3), each SIMD hosts exactly 1 M-wave
//   (matrix ~620 cyc/iter) + 1 V-wave (VALU ~630 cyc/iter) -> overlap
//   gives ~700 cyc/iter vs R7's 1400.
//
//   Flow control: per-pair LDS counters S (st tiles published by M),
//   P (pf tiles published by V), C (pf tiles consumed by M), with 2-slot
//   st/pf double buffers:
//     M iter i: QK(i)->st slot(i&1); S=i+1; prefetch K/bias(i+1);
//               if i>=1 { wait P>=i; read pf(i-1); PV(i-1); C=i; }
//               prefetch V(i).   [slot safety: P>=i (waited at iter i-1)
//               implies st(i-1... i-2) consumed]
//     V iter i: wait S>=i+1; read st(i); exp/pack/lsum;
//               if i>=2 wait C>=i-1; write pf(i) slot(i&1); P=i+1.
//   Deadlock-free: every wait is satisfied one pipeline step behind.
//
//   LDS: st 4p x 2slot x 8KB = 64K; pf 4p x 2slot x 4KB = 32K; flags.
//   Merge (after barrier, reusing st region): V-waves publish lsum;
//   M(kq=1) writes o; M(kq=0) adds, normalizes by total lsum, writes Out.
//   launch_bounds(512,2) -> 256-reg budget (proven safe, R12: no spill).
// ---------------------------------------------------------------------------
__global__ __launch_bounds__(512, 2)
void flash_kernel(const float* __restrict__ Q, const u16* __restrict__ blob,
                  const float* __restrict__ bias2, float* __restrict__ Out) {
    __shared__ __align__(16) char smem[99328];
    // [0,65536): st  — pair*16384 + slot*8192 + v*1024 + lane*16   (v=kt*4+qf)
    // [65536,98304): pf — 65536 + pair*8192 + slot*4096 + qf*1024 + lane*16
    // [98304,99072): flags — pair*192 + {S:+0, P:+64, C:+128}
    // merge (after barrier, aliases st): MO[qh] at qh*17664 ([64][68]+[64]);
    //   LML at 35328: (kq*2+qh)*256 bytes, 64 f32 row-lsums each.

    const int tid = threadIdx.x;
    const int l = tid & 63, low = l & 15, h = l >> 4;
    const int wid = __builtin_amdgcn_readfirstlane(tid >> 6);   // 0..7
    const int isM = (wid < 4);
    const int pair = wid & 3;
    const int kq = pair & 1;            // key half
    const int qh = pair >> 1;           // q half (64 rows)

    const int bid = blockIdx.x;
    const int batch = bid & 3;          // XCD-affinity
    const int qt2 = bid >> 2;           // 0..63 (128-q tiles)
    const int q0 = qt2 * 128 + qh * 64;

    u32* Sf = (u32*)(smem + 98304 + pair * 192);
    u32* Pf = (u32*)(smem + 98304 + pair * 192 + 64);
    u32* Cf = (u32*)(smem + 98304 + pair * 192 + 128);
    if (tid < 192) ((u32*)(smem + 98304))[tid] = 0;
    __syncthreads();

    char* stb0 = smem + pair * 16384;
    char* pfb0 = smem + 65536 + pair * 8192;

    float lsum[4] = {0.f, 0.f, 0.f, 0.f};   // V-wave state
    f32x4 o[4][4];                           // M-wave state
#pragma unroll
    for (int qf = 0; qf < 4; ++qf)
#pragma unroll
        for (int dt = 0; dt < 4; ++dt) o[qf][dt] = (f32x4){0, 0, 0, 0};

    if (isM) {
        // ---- M-wave: Q frags, K/V/bias streaming, all MFMAs ----
        const float qscale = 0.18033688011112042f;
        half8 qfrag[4][2];
#pragma unroll
        for (int qf = 0; qf < 4; ++qf) {
            const float* qrow = Q + ((size_t)(batch * S_LEN + q0 + qf * 16 + low)) * DHEAD + h * 8;
#pragma unroll
            for (int ds = 0; ds < 2; ++ds) {
                f32x4 a = *(const f32x4*)(qrow + ds * 32);
                f32x4 b = *(const f32x4*)(qrow + ds * 32 + 4);
                HU8 u;
                u.w[0] = packh2(a[0] * qscale, a[1] * qscale);
                u.w[1] = packh2(a[2] * qscale, a[3] * qscale);
                u.w[2] = packh2(b[0] * qscale, b[1] * qscale);
                u.w[3] = packh2(b[2] * qscale, b[3] * qscale);
                qfrag[qf][ds] = u.h8;
            }
        }

        const u16* kvb = blob + ((size_t)(batch * 256 + kq * 128)) * 4096;
        const int loff = l * 8;
        const float* bbase = bias2 + kq * 4096;

        HU8 kf[4];
        f32x4 bvv[2];
        HU8 vf[4];

        // prologue: K/bias(0)
#pragma unroll
        for (int j = 0; j < 4; ++j) kf[j].i4 = *(const int4*)(kvb + j * 512 + loff);
        bvv[0] = *(const f32x4*)(bbase + h * 8);
        bvv[1] = *(const f32x4*)(bbase + h * 8 + 4);

#pragma unroll 1
        for (int i = 0; i < KIT; ++i) {
            const u16* tb = kvb + (size_t)i * 4096;
            char* stb = stb0 + (i & 1) * 8192;
            // QK(i) -> st slot
#pragma unroll
            for (int kt = 0; kt < 2; ++kt) {
                const f32x4 binit = kt ? bvv[1] : bvv[0];
#pragma unroll
                for (int qf = 0; qf < 4; ++qf) {
                    f32x4 a = __builtin_amdgcn_mfma_f32_16x16x32_f16(kf[kt * 2].h8, qfrag[qf][0], binit, 0, 0, 0);
                    a = __builtin_amdgcn_mfma_f32_16x16x32_f16(kf[kt * 2 + 1].h8, qfrag[qf][1], a, 0, 0, 0);
                    *(f32x4*)(stb + (kt * 4 + qf) * 1024 + l * 16) = a;
                }
            }
            if (l == 0) ST_REL(Sf, (u32)(i + 1));
            // prefetch K/bias(i+1) (last iter reads pad/neighbor - dead)
            const u16* tn = tb + 4096;
#pragma unroll
            for (int j = 0; j < 4; ++j) kf[j].i4 = *(const int4*)(tn + j * 512 + loff);
            const float* bpn = bbase + (i + 1) * 32 + h * 8;
            bvv[0] = *(const f32x4*)bpn;
            bvv[1] = *(const f32x4*)(bpn + 4);
            // PV(i-1)
            if (i >= 1) {
                while (LD_ACQ(Pf) < (u32)i) __builtin_amdgcn_s_sleep(1);
                char* pfb = pfb0 + ((i - 1) & 1) * 4096;
                HU8 pfr[4];
#pragma unroll
                for (int qf = 0; qf < 4; ++qf) pfr[qf].i4 = *(const int4*)(pfb + qf * 1024 + l * 16);
#pragma unroll
                for (int dt = 0; dt < 4; ++dt)
#pragma unroll
                    for (int qf = 0; qf < 4; ++qf)
                        o[qf][dt] = __builtin_amdgcn_mfma_f32_16x16x32_f16(vf[dt].h8, pfr[qf].h8, o[qf][dt], 0, 0, 0);
                if (l == 0) ST_REL(Cf, (u32)i);
            }
            // prefetch V(i) (used by PV(i) next iter)
#pragma unroll
            for (int j = 0; j < 4; ++j) vf[j].i4 = *(const int4*)(tb + 2048 + j * 512 + loff);
        }
        // epilogue: PV(KIT-1)
        {
            while (LD_ACQ(Pf) < (u32)KIT) __builtin_amdgcn_s_sleep(1);
            char* pfb = pfb0 + ((KIT - 1) & 1) * 4096;
            HU8 pfr[4];
#pragma unroll
            for (int qf = 0; qf < 4; ++qf) pfr[qf].i4 = *(const int4*)(pfb + qf * 1024 + l * 16);
#pragma unroll
            for (int dt = 0; dt < 4; ++dt)
#pragma unroll
                for (int qf = 0; qf < 4; ++qf)
                    o[qf][dt] = __builtin_amdgcn_mfma_f32_16x16x32_f16(vf[dt].h8, pfr[qf].h8, o[qf][dt], 0, 0, 0);
        }
    } else {
        // ---- V-wave: exp2 / pack / lsum only ----
#pragma unroll 1
        for (int i = 0; i < KIT; ++i) {
            while (LD_ACQ(Sf) < (u32)(i + 1)) __builtin_amdgcn_s_sleep(1);
            char* stb = stb0 + (i & 1) * 8192;
            f32x4 stv[8];
#pragma unroll
            for (int v = 0; v < 8; ++v) stv[v] = *(const f32x4*)(stb + v * 1024 + l * 16);
            HU8 pf[4];
#pragma unroll
            for (int kt = 0; kt < 2; ++kt)
#pragma unroll
                for (int qf = 0; qf < 4; ++qf) {
                    const f32x4 s = stv[kt * 4 + qf];
                    float p0 = EXP2(s[0]), p1 = EXP2(s[1]);
                    float p2 = EXP2(s[2]), p3 = EXP2(s[3]);
                    lsum[qf] += (p0 + p1) + (p2 + p3);
                    pf[qf].w[kt * 2]     = packh2(p0, p1);
                    pf[qf].w[kt * 2 + 1] = packh2(p2, p3);
                }
            if (i >= 2) { while (LD_ACQ(Cf) < (u32)(i - 1)) __builtin_amdgcn_s_sleep(1); }
            char* pfb = pfb0 + (i & 1) * 4096;
#pragma unroll
            for (int qf = 0; qf < 4; ++qf)
                *(int4*)(pfb + qf * 1024 + l * 16) = pf[qf].i4;
            if (l == 0) ST_REL(Pf, (u32)(i + 1));
        }
        // finalize lsum across key groups
#pragma unroll
        for (int qf = 0; qf < 4; ++qf) {
            lsum[qf] += __shfl_xor(lsum[qf], 16, 64);
            lsum[qf] += __shfl_xor(lsum[qf], 32, 64);
        }
    }

    // ---- merge (st region reused after barrier) ----
    __syncthreads();
    float* LML = (float*)(smem + 35328);   // (kq*2+qh)*64 row-lsums
    if (!isM) {
        if (h == 0) {
#pragma unroll
            for (int qf = 0; qf < 4; ++qf)
                LML[(kq * 2 + qh) * 64 + qf * 16 + low] = lsum[qf];
        }
    }
    if (isM && kq == 1) {
        float* MO = (float*)(smem + qh * 17664);
#pragma unroll
        for (int qf = 0; qf < 4; ++qf) {
            const int row = qf * 16 + low;
#pragma unroll
            for (int dt = 0; dt < 4; ++dt)
                *(f32x4*)&MO[row * 68 + dt * 16 + h * 4] = o[qf][dt];
        }
    }
    __syncthreads();
    if (isM && kq == 0) {
        float* MO = (float*)(smem + qh * 17664);
#pragma unroll
        for (int qf = 0; qf < 4; ++qf) {
            const int row = qf * 16 + low;
            const float lt = LML[qh * 64 + row] + LML[(2 + qh) * 64 + row];
            const float inv = 1.f / lt;
            float* orow = Out + ((size_t)(batch * S_LEN + q0 + row)) * DHEAD;
#pragma unroll
            for (int dt = 0; dt < 4; ++dt) {
                f32x4 a = *(const f32x4*)&MO[row * 68 + dt * 16 + h * 4];
                f32x4 r;
#pragma unroll
                for (int jj = 0; jj < 4; ++jj) r[jj] = (o[qf][dt][jj] + a[jj]) * inv;
                *(f32x4*)(orow + dt * 16 + h * 4) = r;
            }
        }
    }
}

// ---------------------------------------------------------------------------
extern "C" void kernel_launch(void* const* d_in, const int* in_sizes, int n_in,
                              void* d_out, int out_size, void* d_ws, size_t ws_size,
                              hipStream_t stream) {
    const float* Q  = (const float*)d_in[0];
    const float* K  = (const float*)d_in[1];
    const float* V  = (const float*)d_in[2];
    const float* cr = (const float*)d_in[3];
    const float* ci = (const float*)d_in[4];
    const float* sc = (const float*)d_in[5];
    float* out = (float*)d_out;

    char* ws = (char*)d_ws;
    float* bias2 = (float*)ws;                   // 32 KB + 256 B tail pad  [0, 33024)
    u16*   blob  = (u16*)(ws + 33024);           // 8 MB + 8 KB tail pad

    prep_kernel<<<dim3(1056), dim3(256), 0, stream>>>(K, V, cr, ci, sc, blob, bias2);
    flash_kernel<<<dim3(256), dim3(512), 0, stream>>>(Q, blob, bias2, out);
}

// Round 14
// 190.226 us; speedup vs baseline: 1.0115x; 1.0115x over previous
//
#include <hip/hip_runtime.h>
#include <math.h>

#define S_LEN 8192
#define DHEAD 64
#define NBATCH 4
#define BK 32
#define KIT 128           // 4096 keys per pair / BK

typedef unsigned short u16;
typedef unsigned int u32;
typedef __attribute__((ext_vector_type(8))) _Float16 half8;
typedef __attribute__((ext_vector_type(2))) __fp16 fp16x2;
typedef __attribute__((ext_vector_type(4))) float f32x4;

union HU8 { int4 i4; half8 h8; u32 w[4]; };
union H2U { fp16x2 h2; u32 w; };
union HU  { _Float16 h; u16 u; };

#if __has_builtin(__builtin_amdgcn_exp2f)
#define EXP2(x) __builtin_amdgcn_exp2f(x)
#else
#define EXP2(x) exp2f(x)
#endif

// float -> f16 RNE
__device__ __forceinline__ u16 f2h(float f) {
    HU x; x.h = (_Float16)f; return x.u;
}
// two floats -> packed f16x2, single v_cvt_pkrtz_f16_f32
__device__ __forceinline__ u32 packh2(float a, float b) {
    H2U x; x.h2 = __builtin_amdgcn_cvt_pkrtz(a, b); return x.w;
}

// ---------------------------------------------------------------------------
// Prep: blocks [0,1024) pack K and V (both f16) of one 32-key tile
// (b = bid>>8, t = bid&255) into MFMA-fragment order:
//   blob[b][t] (8 KB) = K chunks j=0..3 (j=kt*2+ds) then V chunks dt=0..3,
//   chunk = 64 lanes x 16 B, exact flash lane order:
//     K: lane(low,h) -> K[b][t*32 + 8*(low>>2)+4*kt+(low&3)][ds*32+h*8+0..7]
//     V: lane(low,h) -> V[b][t*32 + h*8 + 0..7][dt*16+low]
// Blocks [1024,1056): Julia bias in f64 (matches numpy), fixed max M=20
// folded: bias2[k] = log(exp(et*scale)+1e-8)*log2e - 20.
// ---------------------------------------------------------------------------
__global__ void prep_kernel(const float* __restrict__ K, const float* __restrict__ V,
                            const float* crp, const float* cip, const float* scp,
                            u16* __restrict__ blob, float* __restrict__ bias2) {
    int bid = blockIdx.x, tid = threadIdx.x;
    if (bid < 1024) {
        int b = bid >> 8, t = bid & 255;
        __shared__ float Kt[32 * 64];
        __shared__ float Vt[32 * 65];          // padded rows: conflict-free col reads
        int row = tid >> 3, c8 = (tid & 7) * 8;
        const float* ks = K + ((size_t)(b * S_LEN + t * 32 + row)) * 64 + c8;
        const float* vs = V + ((size_t)(b * S_LEN + t * 32 + row)) * 64 + c8;
        float4 ka = *(const float4*)ks, kb4 = *(const float4*)(ks + 4);
        float4 va = *(const float4*)vs, vb4 = *(const float4*)(vs + 4);
        *(float4*)&Kt[row * 64 + c8] = ka;
        *(float4*)&Kt[row * 64 + c8 + 4] = kb4;
        float* vr = &Vt[row * 65 + c8];
        vr[0] = va.x; vr[1] = va.y; vr[2] = va.z; vr[3] = va.w;
        vr[4] = vb4.x; vr[5] = vb4.y; vr[6] = vb4.z; vr[7] = vb4.w;
        __syncthreads();

        int j = tid >> 6, lane = tid & 63, low = lane & 15, h = lane >> 4;
        u16* tb = blob + ((size_t)(b * 256 + t)) * 4096;   // u16 elems (8 KB)
        {   // K chunk j = kt*2 + ds  (f16)
            int kt = j >> 1, ds = j & 1;
            int krow = 8 * (low >> 2) + 4 * kt + (low & 3);
            const float* src = &Kt[krow * 64 + ds * 32 + h * 8];
            u32 wds[4];
#pragma unroll
            for (int i = 0; i < 4; ++i)
                wds[i] = (u32)f2h(src[2 * i]) | ((u32)f2h(src[2 * i + 1]) << 16);
            *(int4*)(tb + j * 512 + lane * 8) = make_int4(wds[0], wds[1], wds[2], wds[3]);
        }
        {   // V chunk dt = j  (f16)
            int col = j * 16 + low;
            u32 wds[4];
#pragma unroll
            for (int i = 0; i < 4; ++i) {
                float a = Vt[(h * 8 + 2 * i) * 65 + col];
                float c = Vt[(h * 8 + 2 * i + 1) * 65 + col];
                wds[i] = (u32)f2h(a) | ((u32)f2h(c) << 16);
            }
            *(int4*)(tb + 2048 + j * 512 + lane * 8) = make_int4(wds[0], wds[1], wds[2], wds[3]);
        }
    } else {
#pragma clang fp contract(off)
        int i = (bid - 1024) * 256 + tid;
        double cr = (double)crp[0], ci = (double)cip[0], sc = (double)scp[0];
        double step = 4.0 / (double)(S_LEN - 1);
        double x = (i == S_LEN - 1) ? 2.0 : (-2.0 + step * (double)i);
        double zr = x, zi = 0.0, et = 1.0;
        bool esc = false;
        for (int it = 0; it < 64; ++it) {
            double nzr = zr * zr - zi * zi + cr;
            double nzi = 2.0 * zr * zi + ci;
            if (!esc) { zr = nzr; zi = nzi; }
            double m2 = zr * zr + zi * zi;
            if (!esc && m2 > 4.0) { et = (double)it / 64.0; esc = true; }
        }
        double bias = log(exp(et * sc) + 1e-8);
        bias2[i] = (float)(bias * 1.4426950408889634 - 20.0);
    }
}

// ---------------------------------------------------------------------------
// Flash: PRODUCER/CONSUMER WAVE SPECIALIZATION, BARRIER-PACED (R14).
//   R13 (same role split, LDS flag+spin sync) ran at 2420 cyc/iter: the
//   acquire/release flags + s_sleep-quantized spins put the full LDS
//   round-trip on the critical path each iteration.  This revision keeps
//   the role split (m114: pure-MFMA wave + pure-VALU wave on one CU overlap
//   fully) but paces the pipeline with ONE __syncthreads() per tile and a
//   2-stage skew so the roles work on DIFFERENT tiles between barriers:
//     iter i, M-wave: QK(i)->st[i&1];  PV(i-2) from pf[i&1] (V wrote it
//                     last phase);  prefetch K/bias(i+1), V(i)->vf[i&1]
//     iter i, V-wave: SM(i-1): read st[(i-1)&1], exp/pack/lsum,
//                     write pf[(i-1)&1]
//     __syncthreads()
//   Slot parities are disjoint by construction (st: write P / read P^1;
//   pf: write P^1 / read P); every dependency is satisfied exactly one
//   barrier behind -- no flags, no spins, no atomics.
//   Per-iter wall = max(M: 32 MFMA ~563 cyc + LDS, V: ~650 VALU) + barrier
//   ~ 750 cyc -> ~41 us ideal flash.  Barrier vmcnt(0) drain is harmless:
//   prefetches issue ~400 cyc earlier and blob is L2-resident.
//
//   Geometry (= R13): grid 256 (1 block/CU), block 512 = 8 waves = 4 pairs;
//   block = 128 q x 8192 keys; pair (qh,kq) = 64 q x 4096 keys, KIT=128.
//   Roles: wid<4 = M (all MFMA), wid>=4 = V (all exp2); SIMD = wid&3 ->
//   each SIMD hosts 1 M + 1 V.  launch_bounds(512,2) (proven: no spill).
//   LDS: st 4x2x8KB=64K, pf 4x2x4KB=32K; merge aliases st after barrier.
// ---------------------------------------------------------------------------
__global__ __launch_bounds__(512, 2)
void flash_kernel(const float* __restrict__ Q, const u16* __restrict__ blob,
                  const float* __restrict__ bias2, float* __restrict__ Out) {
    __shared__ __align__(16) char smem[98304];
    // [0,65536): st  — pair*16384 + slot*8192 + v*1024 + lane*16  (v=kt*4+qf)
    // [65536,98304): pf — 65536 + pair*8192 + slot*4096 + qf*1024 + lane*16
    // merge (aliases st): MO[qh] at qh*17664; LML at 35328 (4 x 64 f32)

    const int tid = threadIdx.x;
    const int l = tid & 63, low = l & 15, h = l >> 4;
    const int wid = __builtin_amdgcn_readfirstlane(tid >> 6);   // 0..7
    const int isM = (wid < 4);
    const int pair = wid & 3;
    const int kq = pair & 1;            // key half
    const int qh = pair >> 1;           // q half (64 rows)

    const int bid = blockIdx.x;
    const int batch = bid & 3;          // XCD-affinity
    const int qt2 = bid >> 2;           // 0..63 (128-q tiles)
    const int q0 = qt2 * 128 + qh * 64;

    char* stb0 = smem + pair * 16384;
    char* pfb0 = smem + 65536 + pair * 8192;

    float lsum[4] = {0.f, 0.f, 0.f, 0.f};   // V-wave state
    f32x4 o[4][4];                           // M-wave state
#pragma unroll
    for (int qf = 0; qf < 4; ++qf)
#pragma unroll
        for (int dt = 0; dt < 4; ++dt) o[qf][dt] = (f32x4){0, 0, 0, 0};

    // ---- M-wave streaming state (declared for all; only M uses) ----
    const float qscale = 0.18033688011112042f;
    half8 qfrag[4][2];
    HU8 kf[4];
    f32x4 bvv[2];
    HU8 vfA[4], vfB[4];                      // V-tile regs by parity
    const u16* kvb = blob + ((size_t)(batch * 256 + kq * 128)) * 4096;
    const int loff = l * 8;
    const float* bbase = bias2 + kq * 4096;

    if (isM) {
#pragma unroll
        for (int qf = 0; qf < 4; ++qf) {
            const float* qrow = Q + ((size_t)(batch * S_LEN + q0 + qf * 16 + low)) * DHEAD + h * 8;
#pragma unroll
            for (int ds = 0; ds < 2; ++ds) {
                f32x4 a = *(const f32x4*)(qrow + ds * 32);
                f32x4 b = *(const f32x4*)(qrow + ds * 32 + 4);
                HU8 u;
                u.w[0] = packh2(a[0] * qscale, a[1] * qscale);
                u.w[1] = packh2(a[2] * qscale, a[3] * qscale);
                u.w[2] = packh2(b[0] * qscale, b[1] * qscale);
                u.w[3] = packh2(b[2] * qscale, b[3] * qscale);
                qfrag[qf][ds] = u.h8;
            }
        }
        // prologue: K/bias(0)
#pragma unroll
        for (int j = 0; j < 4; ++j) kf[j].i4 = *(const int4*)(kvb + j * 512 + loff);
        bvv[0] = *(const f32x4*)(bbase + h * 8);
        bvv[1] = *(const f32x4*)(bbase + h * 8 + 4);
    }

    // STEP(I, PAR, VFP): one tile-slot of the barrier-paced pipeline.
    //   M: QK(I)->st[PAR] (I<KIT); prefetch K/bias(I+1); PV(I-2) from
    //      pf[PAR] with VFP (I>=2); load V(I)->VFP (I<KIT, WAR-renamed).
    //   V: SM(I-1) st[PAR^1] -> pf[PAR^1]  (1<=I<=KIT).
    //   Barrier closes the phase.
#define STEP(I, PAR, VFP)                                                        \
    {                                                                            \
        if (isM) {                                                               \
            const u16* tb_ = kvb + (size_t)(I) * 4096;                           \
            if ((I) < KIT) {                                                     \
                char* stb_ = stb0 + (PAR) * 8192;                                \
                _Pragma("unroll")                                                \
                for (int kt = 0; kt < 2; ++kt) {                                 \
                    const f32x4 binit = kt ? bvv[1] : bvv[0];                    \
                    _Pragma("unroll")                                            \
                    for (int qf = 0; qf < 4; ++qf) {                             \
                        f32x4 a = __builtin_amdgcn_mfma_f32_16x16x32_f16(        \
                            kf[kt * 2].h8, qfrag[qf][0], binit, 0, 0, 0);        \
                        a = __builtin_amdgcn_mfma_f32_16x16x32_f16(              \
                            kf[kt * 2 + 1].h8, qfrag[qf][1], a, 0, 0, 0);        \
                        *(f32x4*)(stb_ + (kt * 4 + qf) * 1024 + l * 16) = a;     \
                    }                                                            \
                }                                                                \
                const u16* tn_ = tb_ + 4096;                                     \
                _Pragma("unroll")                                                \
                for (int j = 0; j < 4; ++j)                                      \
                    kf[j].i4 = *(const int4*)(tn_ + j * 512 + loff);             \
                const float* bpn_ = bbase + ((I) + 1) * 32 + h * 8;              \
                bvv[0] = *(const f32x4*)bpn_;                                    \
                bvv[1] = *(const f32x4*)(bpn_ + 4);                              \
            }                                                                    \
            if ((I) >= 2) {                                                      \
                char* pfb_ = pfb0 + (PAR) * 4096;                                \
                HU8 pfr[4];                                                      \
                _Pragma("unroll")                                                \
                for (int qf = 0; qf < 4; ++qf)                                   \
                    pfr[qf].i4 = *(const int4*)(pfb_ + qf * 1024 + l * 16);      \
                _Pragma("unroll")                                                \
                for (int dt = 0; dt < 4; ++dt)                                   \
                    _Pragma("unroll")                                            \
                    for (int qf = 0; qf < 4; ++qf)                               \
                        o[qf][dt] = __builtin_amdgcn_mfma_f32_16x16x32_f16(      \
                            VFP[dt].h8, pfr[qf].h8, o[qf][dt], 0, 0, 0);         \
            }                                                                    \
            if ((I) < KIT) {                                                     \
                _Pragma("unroll")                                                \
                for (int j = 0; j < 4; ++j)                                      \
                    VFP[j].i4 = *(const int4*)(tb_ + 2048 + j * 512 + loff);     \
            }                                                                    \
        } else {                                                                 \
            if ((I) >= 1 && (I) <= KIT) {                                        \
                char* stb_ = stb0 + ((PAR) ^ 1) * 8192;                          \
                f32x4 stv[8];                                                    \
                _Pragma("unroll")                                                \
                for (int v = 0; v < 8; ++v)                                      \
                    stv[v] = *(const f32x4*)(stb_ + v * 1024 + l * 16);          \
                HU8 pw[4];                                                       \
                _Pragma("unroll")                                                \
                for (int kt = 0; kt < 2; ++kt)                                   \
                    _Pragma("unroll")                                            \
                    for (int qf = 0; qf < 4; ++qf) {                             \
                        const f32x4 s = stv[kt * 4 + qf];                        \
                        float p0 = EXP2(s[0]), p1 = EXP2(s[1]);                  \
                        float p2 = EXP2(s[2]), p3 = EXP2(s[3]);                  \
                        lsum[qf] += (p0 + p1) + (p2 + p3);                       \
                        pw[qf].w[kt * 2]     = packh2(p0, p1);                   \
                        pw[qf].w[kt * 2 + 1] = packh2(p2, p3);                   \
                    }                                                            \
                char* pfb_ = pfb0 + ((PAR) ^ 1) * 4096;                          \
                _Pragma("unroll")                                                \
                for (int qf = 0; qf < 4; ++qf)                                   \
                    *(int4*)(pfb_ + qf * 1024 + l * 16) = pw[qf].i4;             \
            }                                                                    \
        }                                                                        \
        __syncthreads();                                                         \
    }

    // pipeline: I = 0 .. KIT+1  (KIT even -> pairs align)
#pragma unroll 1
    for (int ip = 0; ip < (KIT + 2) / 2; ++ip) {
        const int i0 = 2 * ip;
        STEP(i0, 0, vfA)
        STEP(i0 + 1, 1, vfB)
    }
#undef STEP

    // ---- V-waves: finalize lsum across the 4 key-row groups ----
    if (!isM) {
#pragma unroll
        for (int qf = 0; qf < 4; ++qf) {
            lsum[qf] += __shfl_xor(lsum[qf], 16, 64);
            lsum[qf] += __shfl_xor(lsum[qf], 32, 64);
        }
    }

    // ---- merge (st region reused; loop ended with a barrier) ----
    float* LML = (float*)(smem + 35328);   // (kq*2+qh)*64 row-lsums
    if (!isM) {
        if (h == 0) {
#pragma unroll
            for (int qf = 0; qf < 4; ++qf)
                LML[(kq * 2 + qh) * 64 + qf * 16 + low] = lsum[qf];
        }
    }
    if (isM && kq == 1) {
        float* MO = (float*)(smem + qh * 17664);
#pragma unroll
        for (int qf = 0; qf < 4; ++qf) {
            const int row = qf * 16 + low;
#pragma unroll
            for (int dt = 0; dt < 4; ++dt)
                *(f32x4*)&MO[row * 68 + dt * 16 + h * 4] = o[qf][dt];
        }
    }
    __syncthreads();
    if (isM && kq == 0) {
        float* MO = (float*)(smem + qh * 17664);
#pragma unroll
        for (int qf = 0; qf < 4; ++qf) {
            const int row = qf * 16 + low;
            const float lt = LML[qh * 64 + row] + LML[(2 + qh) * 64 + row];
            const float inv = 1.f / lt;
            float* orow = Out + ((size_t)(batch * S_LEN + q0 + row)) * DHEAD;
#pragma unroll
            for (int dt = 0; dt < 4; ++dt) {
                f32x4 a = *(const f32x4*)&MO[row * 68 + dt * 16 + h * 4];
                f32x4 r;
#pragma unroll
                for (int jj = 0; jj < 4; ++jj) r[jj] = (o[qf][dt][jj] + a[jj]) * inv;
                *(f32x4*)(orow + dt * 16 + h * 4) = r;
            }
        }
    }
}

// ---------------------------------------------------------------------------
extern "C" void kernel_launch(void* const* d_in, const int* in_sizes, int n_in,
                              void* d_out, int out_size, void* d_ws, size_t ws_size,
                              hipStream_t stream) {
    const float* Q  = (const float*)d_in[0];
    const float* K  = (const float*)d_in[1];
    const float* V  = (const float*)d_in[2];
    const float* cr = (const float*)d_in[3];
    const float* ci = (const float*)d_in[4];
    const float* sc = (const float*)d_in[5];
    float* out = (float*)d_out;

    char* ws = (char*)d_ws;
    float* bias2 = (float*)ws;                   // 32 KB + 256 B tail pad  [0, 33024)
    u16*   blob  = (u16*)(ws + 33024);           // 8 MB + 8 KB tail pad

    prep_kernel<<<dim3(1056), dim3(256), 0, stream>>>(K, V, cr, ci, sc, blob, bias2);
    flash_kernel<<<dim3(256), dim3(512), 0, stream>>>(Q, blob, bias2, out);
}

// Round 15
// 153.871 us; speedup vs baseline: 1.2505x; 1.2363x over previous
//
#include <hip/hip_runtime.h>
#include <math.h>

#define S_LEN 8192
#define DHEAD 64
#define NBATCH 4
#define BK 32
#define KIT 64            // 2048 keys per kq-quarter / BK

typedef unsigned short u16;
typedef unsigned int u32;
typedef __attribute__((ext_vector_type(8))) _Float16 half8;
typedef __attribute__((ext_vector_type(2))) __fp16 fp16x2;
typedef __attribute__((ext_vector_type(4))) float f32x4;

union HU8 { int4 i4; half8 h8; u32 w[4]; };
union H2U { fp16x2 h2; u32 w; };
union HU  { _Float16 h; u16 u; };

#if __has_builtin(__builtin_amdgcn_exp2f)
#define EXP2(x) __builtin_amdgcn_exp2f(x)
#else
#define EXP2(x) exp2f(x)
#endif

// float -> f16 RNE
__device__ __forceinline__ u16 f2h(float f) {
    HU x; x.h = (_Float16)f; return x.u;
}
// two floats -> packed f16x2, single v_cvt_pkrtz_f16_f32
__device__ __forceinline__ u32 packh2(float a, float b) {
    H2U x; x.h2 = __builtin_amdgcn_cvt_pkrtz(a, b); return x.w;
}

// ---------------------------------------------------------------------------
// Prep: blocks [0,1024) pack K and V (both f16) of one 32-key tile
// (b = bid>>8, t = bid&255) into MFMA-fragment order:
//   blob[b][t] (8 KB) = K chunks j=0..3 (j=kt*2+ds) then V chunks dt=0..3,
//   chunk = 64 lanes x 16 B, exact flash lane order:
//     K: lane(low,h) -> K[b][t*32 + 8*(low>>2)+4*kt+(low&3)][ds*32+h*8+0..7]
//     V: lane(low,h) -> V[b][t*32 + h*8 + 0..7][dt*16+low]
// Blocks [1024,1056): Julia bias in f64 (matches numpy), fixed max M=20
// folded: bias2[k] = log(exp(et*scale)+1e-8)*log2e - 20.
// ---------------------------------------------------------------------------
__global__ void prep_kernel(const float* __restrict__ K, const float* __restrict__ V,
                            const float* crp, const float* cip, const float* scp,
                            u16* __restrict__ blob, float* __restrict__ bias2) {
    int bid = blockIdx.x, tid = threadIdx.x;
    if (bid < 1024) {
        int b = bid >> 8, t = bid & 255;
        __shared__ float Kt[32 * 64];
        __shared__ float Vt[32 * 65];          // padded rows: conflict-free col reads
        int row = tid >> 3, c8 = (tid & 7) * 8;
        const float* ks = K + ((size_t)(b * S_LEN + t * 32 + row)) * 64 + c8;
        const float* vs = V + ((size_t)(b * S_LEN + t * 32 + row)) * 64 + c8;
        float4 ka = *(const float4*)ks, kb4 = *(const float4*)(ks + 4);
        float4 va = *(const float4*)vs, vb4 = *(const float4*)(vs + 4);
        *(float4*)&Kt[row * 64 + c8] = ka;
        *(float4*)&Kt[row * 64 + c8 + 4] = kb4;
        float* vr = &Vt[row * 65 + c8];
        vr[0] = va.x; vr[1] = va.y; vr[2] = va.z; vr[3] = va.w;
        vr[4] = vb4.x; vr[5] = vb4.y; vr[6] = vb4.z; vr[7] = vb4.w;
        __syncthreads();

        int j = tid >> 6, lane = tid & 63, low = lane & 15, h = lane >> 4;
        u16* tb = blob + ((size_t)(b * 256 + t)) * 4096;   // u16 elems (8 KB)
        {   // K chunk j = kt*2 + ds  (f16)
            int kt = j >> 1, ds = j & 1;
            int krow = 8 * (low >> 2) + 4 * kt + (low & 3);
            const float* src = &Kt[krow * 64 + ds * 32 + h * 8];
            u32 wds[4];
#pragma unroll
            for (int i = 0; i < 4; ++i)
                wds[i] = (u32)f2h(src[2 * i]) | ((u32)f2h(src[2 * i + 1]) << 16);
            *(int4*)(tb + j * 512 + lane * 8) = make_int4(wds[0], wds[1], wds[2], wds[3]);
        }
        {   // V chunk dt = j  (f16)
            int col = j * 16 + low;
            u32 wds[4];
#pragma unroll
            for (int i = 0; i < 4; ++i) {
                float a = Vt[(h * 8 + 2 * i) * 65 + col];
                float c = Vt[(h * 8 + 2 * i + 1) * 65 + col];
                wds[i] = (u32)f2h(a) | ((u32)f2h(c) << 16);
            }
            *(int4*)(tb + 2048 + j * 512 + lane * 8) = make_int4(wds[0], wds[1], wds[2], wds[3]);
        }
    } else {
#pragma clang fp contract(off)
        int i = (bid - 1024) * 256 + tid;
        double cr = (double)crp[0], ci = (double)cip[0], sc = (double)scp[0];
        double step = 4.0 / (double)(S_LEN - 1);
        double x = (i == S_LEN - 1) ? 2.0 : (-2.0 + step * (double)i);
        double zr = x, zi = 0.0, et = 1.0;
        bool esc = false;
        for (int it = 0; it < 64; ++it) {
            double nzr = zr * zr - zi * zi + cr;
            double nzi = 2.0 * zr * zi + ci;
            if (!esc) { zr = nzr; zi = nzi; }
            double m2 = zr * zr + zi * zi;
            if (!esc && m2 > 4.0) { et = (double)it / 64.0; esc = true; }
        }
        double bias = log(exp(et * sc) + 1e-8);
        bias2[i] = (float)(bias * 1.4426950408889634 - 20.0);
    }
}

// ---------------------------------------------------------------------------
// Flash: packed-fragment streaming, no LDS / no barriers in the main loop.
//   grid 512 (2 blocks/CU), block 256 = 4 waves = 4 kq; each wave covers the
//   block's 64 q-rows (4 q-frags) x its 2048-key quarter, BK=32, 64 iters.
//
//   == R7 kernel (best: 75 us flash) + CROSS-BLOCK HALF-ITERATION SKEW ==
//   Evidence through R14: per-wave iteration chain ~1400 cyc vs pipe-sum
//   1193 (85% dense); all overlap attempts failed -- same-wave interleave
//   (R8 spill, R9 null, R11 -22%), SGB pin (-22%), intra-block skew (R12
//   null), flag role-split (R13 -72%), barrier role-split (R14 -60%).
//   Last untested configuration: in THIS geometry the two co-SIMD waves
//   come from TWO DIFFERENT BLOCKS (each 4-wave block maps wave kq to
//   SIMD kq; the CU's 2nd block does the same).  R12 never tested
//   cross-block skew.  Blocks with odd qtile-bit sleep ~704 cyc (half an
//   iteration) after the prologue: ~50% of CUs then host opposite-parity
//   block pairs whose wave pairs run anti-phased (A's MFMA bursts fill
//   B's SM VALU phase).  If lockstep is an attractor this is null and R7
//   is the practical plateau.
//
//   Pipeline order per iteration: QK(i) -> SM(i-1) -> PV(i-1); K/V/bias
//   single-declared (compiler renames across WAR = free double-buffer);
//   st double-buffered via stA/stB odd/even bodies.  launch_bounds(256,2)
//   (only known-good occupancy setting).  All operands f16; fixed-max
//   softmax (M=20 folded into bias); 4-way split-K merged through LDS.
// ---------------------------------------------------------------------------
__global__ __launch_bounds__(256, 2)
void flash_kernel(const float* __restrict__ Q, const u16* __restrict__ blob,
                  const float* __restrict__ bias2, float* __restrict__ Out) {
    __shared__ __align__(16) char smem[17664];   // merge scratch only

    const int tid = threadIdx.x;
    const int l = tid & 63, low = l & 15, h = l >> 4;
    const int kq = __builtin_amdgcn_readfirstlane(tid >> 6);

    const int bid = blockIdx.x;
    const int batch = bid & 3;          // XCD-affinity: batch b on XCDs {b, b+4}
    const int qtile = bid >> 2;         // 0..127 (BQ = 64)
    const int q0 = qtile * 64;

    // ---- Q fragments (4 x 16 q-rows, f16), scale log2(e)/8 folded ----
    const float qscale = 0.18033688011112042f;
    half8 qfrag[4][2];
#pragma unroll
    for (int qf = 0; qf < 4; ++qf) {
        const float* qrow = Q + ((size_t)(batch * S_LEN + q0 + qf * 16 + low)) * DHEAD + h * 8;
#pragma unroll
        for (int ds = 0; ds < 2; ++ds) {
            f32x4 a = *(const f32x4*)(qrow + ds * 32);
            f32x4 b = *(const f32x4*)(qrow + ds * 32 + 4);
            HU8 u;
            u.w[0] = packh2(a[0] * qscale, a[1] * qscale);
            u.w[1] = packh2(a[2] * qscale, a[3] * qscale);
            u.w[2] = packh2(b[0] * qscale, b[1] * qscale);
            u.w[3] = packh2(b[2] * qscale, b[3] * qscale);
            qfrag[qf][ds] = u.h8;
        }
    }

    // wave-uniform stream base (SGPR) + single lane offset (VGPR)
    const u16* kvb = blob + ((size_t)(batch * 256 + kq * 64)) * 4096;
    const int loff = l * 8;                         // u16 elems (16 B/lane)
    const float* bbase = bias2 + kq * 2048;

    f32x4 o[4][4];
#pragma unroll
    for (int qf = 0; qf < 4; ++qf)
#pragma unroll
        for (int dt = 0; dt < 4; ++dt) o[qf][dt] = (f32x4){0, 0, 0, 0};
    float lsum[4] = {0.f, 0.f, 0.f, 0.f};

    HU8 kf[4];           // K buffer (compiler renames across WAR)
    f32x4 bvv[2];        // bias buffer
    HU8 vf[4];           // V buffer
    HU8 pf[4];           // P frags (SM output, PV input)
    f32x4 stA[2][4];     // score buffers: st(i) lives until SM in iter i+1
    f32x4 stB[2][4];

    // ---- prologue: QK(0) -> stA; issue K/bias(1), V(0) ----
#pragma unroll
    for (int j = 0; j < 4; ++j) kf[j].i4 = *(const int4*)(kvb + j * 512 + loff);
    bvv[0] = *(const f32x4*)(bbase + h * 8);
    bvv[1] = *(const f32x4*)(bbase + h * 8 + 4);
#pragma unroll
    for (int kt = 0; kt < 2; ++kt) {
        const f32x4 binit = kt ? bvv[1] : bvv[0];
#pragma unroll
        for (int qf = 0; qf < 4; ++qf) {
            f32x4 a = __builtin_amdgcn_mfma_f32_16x16x32_f16(kf[kt * 2].h8, qfrag[qf][0], binit, 0, 0, 0);
            a = __builtin_amdgcn_mfma_f32_16x16x32_f16(kf[kt * 2 + 1].h8, qfrag[qf][1], a, 0, 0, 0);
            stA[kt][qf] = a;
        }
    }
#pragma unroll
    for (int j = 0; j < 4; ++j) kf[j].i4 = *(const int4*)(kvb + 4096 + j * 512 + loff);
    bvv[0] = *(const f32x4*)(bbase + 32 + h * 8);
    bvv[1] = *(const f32x4*)(bbase + 32 + h * 8 + 4);
#pragma unroll
    for (int j = 0; j < 4; ++j) vf[j].i4 = *(const int4*)(kvb + 2048 + j * 512 + loff);

    // ---- cross-block anti-phase skew: odd-qtile-bit blocks delay ~704 cyc
    //      (half the measured 1400-cyc iteration).  ~50% of CUs will pair
    //      opposite-parity blocks -> their SIMD wave pairs run anti-phased.
    //      No barriers in the main loop, so the skew persists. ----
    if ((bid >> 3) & 1) __builtin_amdgcn_s_sleep(11);

    // BODY(KI, STC, STP):
    //   QK(KI) -> STC            (kf=K(KI), bvv=bias(KI))
    //   issue K/bias(KI+1)       (kf/bvv WAR -> compiler renames)
    //   SM(KI-1) from STP -> pf  (scores one full iter old: no stall)
    //   PV(KI-1)                 (vf=V(KI-1))
    //   issue V(KI) -> vf
#define BODY(KI, STC, STP)                                                       \
    {                                                                            \
        const u16* tb_ = kvb + (size_t)(KI) * 4096;                              \
        const u16* tn_ = tb_ + 4096;                                             \
        _Pragma("unroll")                                                        \
        for (int kt = 0; kt < 2; ++kt) {                                         \
            const f32x4 binit = kt ? bvv[1] : bvv[0];                            \
            _Pragma("unroll")                                                    \
            for (int qf = 0; qf < 4; ++qf) {                                     \
                f32x4 a = __builtin_amdgcn_mfma_f32_16x16x32_f16(                \
                    kf[kt * 2].h8, qfrag[qf][0], binit, 0, 0, 0);                \
                a = __builtin_amdgcn_mfma_f32_16x16x32_f16(                      \
                    kf[kt * 2 + 1].h8, qfrag[qf][1], a, 0, 0, 0);                \
                STC[kt][qf] = a;                                                 \
            }                                                                    \
        }                                                                        \
        _Pragma("unroll")                                                        \
        for (int j = 0; j < 4; ++j)                                              \
            kf[j].i4 = *(const int4*)(tn_ + j * 512 + loff);                     \
        const float* bpn_ = bbase + ((KI) + 1) * 32 + h * 8;                     \
        bvv[0] = *(const f32x4*)bpn_;                                            \
        bvv[1] = *(const f32x4*)(bpn_ + 4);                                      \
        _Pragma("unroll")                                                        \
        for (int kt = 0; kt < 2; ++kt)                                           \
            _Pragma("unroll")                                                    \
            for (int qf = 0; qf < 4; ++qf) {                                     \
                float p0 = EXP2(STP[kt][qf][0]), p1 = EXP2(STP[kt][qf][1]);      \
                float p2 = EXP2(STP[kt][qf][2]), p3 = EXP2(STP[kt][qf][3]);      \
                lsum[qf] += (p0 + p1) + (p2 + p3);                               \
                pf[qf].w[kt * 2]     = packh2(p0, p1);                           \
                pf[qf].w[kt * 2 + 1] = packh2(p2, p3);                           \
            }                                                                    \
        _Pragma("unroll")                                                        \
        for (int dt = 0; dt < 4; ++dt)                                           \
            _Pragma("unroll")                                                    \
            for (int qf = 0; qf < 4; ++qf)                                       \
                o[qf][dt] = __builtin_amdgcn_mfma_f32_16x16x32_f16(              \
                    vf[dt].h8, pf[qf].h8, o[qf][dt], 0, 0, 0);                   \
        _Pragma("unroll")                                                        \
        for (int j = 0; j < 4; ++j)                                              \
            vf[j].i4 = *(const int4*)(tb_ + 2048 + j * 512 + loff);              \
    }

    // bodies 1..62 in odd/even pairs, then body 63 (its K/bias(64) prefetch
    // reads blob/bias tail pad -- dead values)
#pragma unroll 1
    for (int kp = 1; kp < KIT - 1; kp += 2) {
        BODY(kp, stB, stA)
        BODY(kp + 1, stA, stB)
    }
    BODY(KIT - 1, stB, stA)
#undef BODY

    // ---- epilogue: SM(63) from stB, PV(63) ----
#pragma unroll
    for (int kt = 0; kt < 2; ++kt)
#pragma unroll
        for (int qf = 0; qf < 4; ++qf) {
            float p0 = EXP2(stB[kt][qf][0]), p1 = EXP2(stB[kt][qf][1]);
            float p2 = EXP2(stB[kt][qf][2]), p3 = EXP2(stB[kt][qf][3]);
            lsum[qf] += (p0 + p1) + (p2 + p3);
            pf[qf].w[kt * 2]     = packh2(p0, p1);
            pf[qf].w[kt * 2 + 1] = packh2(p2, p3);
        }
#pragma unroll
    for (int dt = 0; dt < 4; ++dt)
#pragma unroll
        for (int qf = 0; qf < 4; ++qf)
            o[qf][dt] = __builtin_amdgcn_mfma_f32_16x16x32_f16(vf[dt].h8, pf[qf].h8, o[qf][dt], 0, 0, 0);

    // ---- finalize l ----
#pragma unroll
    for (int qf = 0; qf < 4; ++qf) {
        lsum[qf] += __shfl_xor(lsum[qf], 16, 64);
        lsum[qf] += __shfl_xor(lsum[qf], 32, 64);
    }

    // ---- split-K merge: partials add linearly (fixed max). 3 stages. ----
    float* MO = (float*)smem;              // [64][68]
    float* ML = (float*)(smem + 17408);    // [64]
#pragma unroll 1
    for (int src = 1; src < 4; ++src) {
        __syncthreads();
        if (kq == src) {
#pragma unroll
            for (int qf = 0; qf < 4; ++qf) {
                const int row = qf * 16 + low;
#pragma unroll
                for (int dt = 0; dt < 4; ++dt)
                    *(f32x4*)&MO[row * 68 + dt * 16 + h * 4] = o[qf][dt];
                if (h == 0) ML[row] = lsum[qf];
            }
        }
        __syncthreads();
        if (kq == 0) {
#pragma unroll
            for (int qf = 0; qf < 4; ++qf) {
                const int row = qf * 16 + low;
#pragma unroll
                for (int dt = 0; dt < 4; ++dt) {
                    f32x4 a = *(const f32x4*)&MO[row * 68 + dt * 16 + h * 4];
#pragma unroll
                    for (int jj = 0; jj < 4; ++jj) o[qf][dt][jj] += a[jj];
                }
                lsum[qf] += ML[row];
            }
        }
    }

    if (kq == 0) {
#pragma unroll
        for (int qf = 0; qf < 4; ++qf) {
            const float inv = 1.f / lsum[qf];
            float* orow = Out + ((size_t)(batch * S_LEN + q0 + qf * 16 + low)) * DHEAD;
#pragma unroll
            for (int dt = 0; dt < 4; ++dt) {
                f32x4 r;
#pragma unroll
                for (int jj = 0; jj < 4; ++jj) r[jj] = o[qf][dt][jj] * inv;
                *(f32x4*)(orow + dt * 16 + h * 4) = r;
            }
        }
    }
}

// ---------------------------------------------------------------------------
extern "C" void kernel_launch(void* const* d_in, const int* in_sizes, int n_in,
                              void* d_out, int out_size, void* d_ws, size_t ws_size,
                              hipStream_t stream) {
    const float* Q  = (const float*)d_in[0];
    const float* K  = (const float*)d_in[1];
    const float* V  = (const float*)d_in[2];
    const float* cr = (const float*)d_in[3];
    const float* ci = (const float*)d_in[4];
    const float* sc = (const float*)d_in[5];
    float* out = (float*)d_out;

    char* ws = (char*)d_ws;
    float* bias2 = (float*)ws;                   // 32 KB + 256 B tail pad  [0, 33024)
    u16*   blob  = (u16*)(ws + 33024);           // 8 MB + 8 KB tail pad

    prep_kernel<<<dim3(1056), dim3(256), 0, stream>>>(K, V, cr, ci, sc, blob, bias2);
    flash_kernel<<<dim3(512), dim3(256), 0, stream>>>(Q, blob, bias2, out);
}